// Round 3
// baseline (12657.640 us; speedup 1.0000x reference)
//
#include <hip/hip_runtime.h>

// B=2048, T=128, D=5, H=256.
// Round 3: gate-split groups of 4 workgroups. Each group owns 16 batch rows;
// member m of a group computes gate rows {i,f,g,o}x[64m,64m+64) with its
// weight quarter (144 KB) fully REGISTER-resident (~72 VGPR/wave of weights).
// Per step, members exchange their 16x64 bf16 h-slices (2 KB) through global
// memory with agent-scope release/acquire flags. Grid 512x256 (all waves
// co-resident: 8 waves/CU), so spin-wait cannot deadlock.

typedef __bf16 bf16x8 __attribute__((ext_vector_type(8)));
typedef float f32x4 __attribute__((ext_vector_type(4)));

#define MFMA16(A, B, C) __builtin_amdgcn_mfma_f32_16x16x32_bf16((A), (B), (C), 0, 0, 0)

__device__ __forceinline__ float fast_sigmoid(float x) {
  float e = __builtin_amdgcn_exp2f(-1.4426950408889634f * x);
  return __builtin_amdgcn_rcpf(1.0f + e);
}
__device__ __forceinline__ float fast_tanh(float x) {
  float e = __builtin_amdgcn_exp2f(2.8853900817779268f * x);
  return 1.0f - 2.0f * __builtin_amdgcn_rcpf(e + 1.0f);
}
__device__ __forceinline__ float lrelu(float x) { return x >= 0.0f ? x : 0.01f * x; }

// ---------------- prep: pack weights ----------------
// frag (mm,T,s,c,lane): 8 bf16 = W[g = T*256+mm*64+s*16+(lane&15)][k = c*32+(lane>>4)*8 .. +7]
__global__ void pack_gates_k(const float* __restrict__ Whh, const float* __restrict__ Wih,
                             const float* __restrict__ bih, const float* __restrict__ bhh,
                             __bf16* __restrict__ wpack, __bf16* __restrict__ ihpack,
                             float* __restrict__ bias) {
  int lane = threadIdx.x, blk = blockIdx.x;
  if (blk < 512) {
    int mm = blk >> 7, T = (blk >> 5) & 3, s = (blk >> 3) & 3, c = blk & 7;
    int grow = T * 256 + mm * 64 + s * 16 + (lane & 15);
    int k0 = c * 32 + (lane >> 4) * 8;
    bf16x8 v;
#pragma unroll
    for (int jj = 0; jj < 8; ++jj) v[jj] = (__bf16)Whh[grow * 256 + k0 + jj];
    *(bf16x8*)(wpack + ((size_t)blk * 64 + lane) * 8) = v;
  } else if (blk < 576) {
    int idx = blk - 512;
    int mm = idx >> 4, T = (idx >> 2) & 3, s = idx & 3;
    int grow = T * 256 + mm * 64 + s * 16 + (lane & 15);
    int kk = (lane >> 4) * 8;
    bf16x8 v;
#pragma unroll
    for (int jj = 0; jj < 8; ++jj)
      v[jj] = (kk + jj < 5) ? (__bf16)Wih[grow * 5 + kk + jj] : (__bf16)0.0f;
    *(bf16x8*)(ihpack + ((size_t)idx * 64 + lane) * 8) = v;
  } else {
    int gg = (blk - 576) * 64 + lane;
    bias[gg] = bih[gg] + bhh[gg];
  }
}

__global__ void pack_misc_k(const float* __restrict__ Wenc, const float* __restrict__ Wout,
                            __bf16* __restrict__ encpack, __bf16* __restrict__ outpack) {
  int lane = threadIdx.x, blk = blockIdx.x;
  if (blk < 128) {  // W_enc[:, :256] -> 16 row-tiles x 8 chunks
    int T2 = blk >> 3, c = blk & 7;
    int row = T2 * 16 + (lane & 15);
    int k0 = c * 32 + (lane >> 4) * 8;
    bf16x8 v;
#pragma unroll
    for (int jj = 0; jj < 8; ++jj) v[jj] = (__bf16)Wenc[row * 512 + k0 + jj];
    *(bf16x8*)(encpack + ((size_t)blk * 64 + lane) * 8) = v;
  } else {  // W_out (5x256), zero-padded rows
    int c = blk - 128;
    int d = lane & 15, k0 = c * 32 + (lane >> 4) * 8;
    bf16x8 v;
#pragma unroll
    for (int jj = 0; jj < 8; ++jj)
      v[jj] = (d < 5) ? (__bf16)Wout[d * 256 + k0 + jj] : (__bf16)0.0f;
    *(bf16x8*)(outpack + ((size_t)c * 64 + lane) * 8) = v;
  }
}

// ---------------- main kernel ----------------
__global__ __launch_bounds__(256, 2) void rnn_grp(
    const float* __restrict__ sk, const float* __restrict__ initx,
    const bf16x8* __restrict__ Wg, const bf16x8* __restrict__ IHg, const float* __restrict__ Bg,
    const bf16x8* __restrict__ Wf, const bf16x8* __restrict__ IHf, const float* __restrict__ Bf,
    const bf16x8* __restrict__ Epk, const float* __restrict__ benc,
    const bf16x8* __restrict__ Opk, const float* __restrict__ bout,
    __bf16* __restrict__ hx, unsigned int* __restrict__ flags,
    float* __restrict__ out) {
  // abuf[pingpong][chunk][batchrow][k-in-chunk(+pad)]
  __shared__ __bf16 abuf[2][8][16][40];
  __shared__ __bf16 xt[4][16][8];

  const int tid = threadIdx.x, lane = tid & 63, wv = tid >> 6;
  const int col = lane & 15, lgrp = lane >> 4;
  const int m = blockIdx.x >> 7;   // member 0..3 (gate quarter)
  const int g = blockIdx.x & 127;  // group (16 batch rows)
  const int b0 = g * 16;
  unsigned int* flagp = flags + g * 4;
  __bf16* hxg = hx + (size_t)g * (4 * 4 * 1024);  // [member][slot][2KB]

  for (int i = tid; i < 2 * 8 * 16 * 40; i += 256) (&abuf[0][0][0][0])[i] = (__bf16)0.0f;
  for (int i = tid; i < 4 * 16 * 8; i += 256) (&xt[0][0][0])[i] = (__bf16)0.0f;

  const int u_rel = wv * 16 + col;          // this thread's unit within member slice
  const int ci = 2 * m + (u_rel >> 5);      // abuf chunk for own h writes
  const int ko = u_rel & 31;

  // publish own slice (abuf[f&1] own region) -> hx slot f&3, fence, flag := f
  auto publish = [&](int f) {
    if (wv == m) {
      __bf16* dst = hxg + ((size_t)m * 4 + (f & 3)) * 1024;
      const int pb = f & 1;
#pragma unroll
      for (int q = 0; q < 2; ++q) {
        int idx = q * 64 + lane;
        int cc = idx >> 6, rem = idx & 63, row = rem >> 2, kg = rem & 3;
        bf16x8 v = *(const bf16x8*)&abuf[pb][2 * m + cc][row][kg * 8];
        *(bf16x8*)(dst + idx * 8) = v;
      }
      __threadfence();
      if (lane == 0)
        __hip_atomic_store(flagp + m, (unsigned)f, __ATOMIC_RELEASE, __HIP_MEMORY_SCOPE_AGENT);
    }
  };
  // stage peer slices (wave w pulls member w, w != m) into abuf[f&1]
  auto stage = [&](int f) {
    if (wv != m) {
      const int j = wv;
      while (__hip_atomic_load(flagp + j, __ATOMIC_ACQUIRE, __HIP_MEMORY_SCOPE_AGENT) <
             (unsigned)f)
        __builtin_amdgcn_s_sleep(1);
      const __bf16* src = hxg + ((size_t)j * 4 + (f & 3)) * 1024;
      const int pb = f & 1;
#pragma unroll
      for (int q = 0; q < 2; ++q) {
        int idx = q * 64 + lane;
        int cc = idx >> 6, rem = idx & 63, row = rem >> 2, kg = rem & 3;
        bf16x8 v = *(const bf16x8*)(src + idx * 8);
        *(bf16x8*)&abuf[pb][2 * j + cc][row][kg * 8] = v;
      }
    }
  };

  // ---- encoder weights (register-resident quarter) ----
  bf16x8 wf_[4][8];
  bf16x8 wih_[4];
  float bv_[4];
#pragma unroll
  for (int T = 0; T < 4; ++T) {
#pragma unroll
    for (int c = 0; c < 8; ++c)
      wf_[T][c] = Wf[(size_t)((((m * 4 + T) * 4 + wv) * 8) + c) * 64 + lane];
    wih_[T] = IHf[(size_t)((m * 4 + T) * 4 + wv) * 64 + lane];
    bv_[T] = Bf[T * 256 + m * 64 + wv * 16 + col];
  }
  float c_reg[4] = {0.f, 0.f, 0.f, 0.f};
  __syncthreads();

  // -------- encoder: 128 steps --------
  for (int t = 0; t < 128; ++t) {
    if (t > 0) { publish(t); stage(t); }
    bf16x8 ax = (bf16x8){};
    if (lgrp == 0) {
      const float* xp = sk + ((size_t)(b0 + col) * 128 + t) * 5;
      ax[0] = (__bf16)xp[0]; ax[1] = (__bf16)xp[1]; ax[2] = (__bf16)xp[2];
      ax[3] = (__bf16)xp[3]; ax[4] = (__bf16)xp[4];
    }
    __syncthreads();
    const int pb = t & 1;
    f32x4 acc[4];
#pragma unroll
    for (int T = 0; T < 4; ++T) acc[T] = (f32x4){bv_[T], bv_[T], bv_[T], bv_[T]};
#pragma unroll
    for (int c = 0; c < 8; ++c) {
      bf16x8 a_c = *(const bf16x8*)&abuf[pb][c][col][lgrp * 8];
#pragma unroll
      for (int T = 0; T < 4; ++T) acc[T] = MFMA16(a_c, wf_[T][c], acc[T]);
    }
#pragma unroll
    for (int T = 0; T < 4; ++T) acc[T] = MFMA16(ax, wih_[T], acc[T]);
#pragma unroll
    for (int r = 0; r < 4; ++r) {
      float ig = fast_sigmoid(acc[0][r]);
      float fg = fast_sigmoid(acc[1][r]);
      float gg = fast_tanh(acc[2][r]);
      float og = fast_sigmoid(acc[3][r]);
      float cn = fg * c_reg[r] + ig * gg;
      c_reg[r] = cn;
      abuf[pb ^ 1][ci][lgrp * 4 + r][ko] = (__bf16)(og * fast_tanh(cn));
    }
    __syncthreads();
  }

  // -------- transition --------
  publish(128); stage(128);  // h_f full into abuf[0]
  bf16x8 eb[8];
  float bvh;
  {
    const int T2 = m * 4 + wv;
#pragma unroll
    for (int c = 0; c < 8; ++c) eb[c] = Epk[(size_t)(T2 * 8 + c) * 64 + lane];
    bvh = benc[T2 * 16 + col];
  }
  __syncthreads();
  f32x4 hacc = (f32x4){bvh, bvh, bvh, bvh};
#pragma unroll
  for (int c = 0; c < 8; ++c) {
    bf16x8 a_c = *(const bf16x8*)&abuf[0][c][col][lgrp * 8];
    hacc = MFMA16(a_c, eb[c], hacc);
  }
  // c_f (bf16) into abuf[1] own region
#pragma unroll
  for (int r = 0; r < 4; ++r) abuf[1][ci][lgrp * 4 + r][ko] = (__bf16)c_reg[r];
  __syncthreads();
  publish(129); stage(129);  // c_f full into abuf[1]
  __syncthreads();
  f32x4 cacc = (f32x4){bvh, bvh, bvh, bvh};
#pragma unroll
  for (int c = 0; c < 8; ++c) {
    bf16x8 a_c = *(const bf16x8*)&abuf[1][c][col][lgrp * 8];
    cacc = MFMA16(a_c, eb[c], cacc);
  }
#pragma unroll
  for (int r = 0; r < 4; ++r) c_reg[r] = lrelu(cacc[r]);        // cell -> gen c(0) (same wave owns it)
#pragma unroll
  for (int r = 0; r < 4; ++r)                                   // hidden -> gen h(0) into abuf[0]
    abuf[0][ci][lgrp * 4 + r][ko] = (__bf16)lrelu(hacc[r]);
  __syncthreads();
  publish(130); stage(130);  // gen h(0) full into abuf[0]
  // ---- generator weights ----
  bf16x8 wout_[8];
#pragma unroll
  for (int T = 0; T < 4; ++T) {
#pragma unroll
    for (int c = 0; c < 8; ++c)
      wf_[T][c] = Wg[(size_t)((((m * 4 + T) * 4 + wv) * 8) + c) * 64 + lane];
    wih_[T] = IHg[(size_t)((m * 4 + T) * 4 + wv) * 64 + lane];
    bv_[T] = Bg[T * 256 + m * 64 + wv * 16 + col];
  }
#pragma unroll
  for (int c = 0; c < 8; ++c) wout_[c] = Opk[(size_t)c * 64 + lane];
  const float bo = (col < 5) ? bout[col] : 0.0f;
  __syncthreads();

  // -------- generator: iters j=0..128; iter j consumes h_gen(j), emits out(j-1), h_gen(j+1) --------
  for (int j = 0; j <= 128; ++j) {
    const int f = 130 + j, pb = f & 1;
    if (j > 0) { publish(f); stage(f); }
    float ix0 = 0, ix1 = 0, ix2 = 0, ix3 = 0, ix4 = 0;
    if (j == 0 && lgrp == 0) {
      const float* xp = initx + (b0 + col) * 5;
      ix0 = xp[0]; ix1 = xp[1]; ix2 = xp[2]; ix3 = xp[3]; ix4 = xp[4];
    }
    __syncthreads();
    f32x4 oacc = (f32x4){bo, bo, bo, bo};
    f32x4 acc[4];
#pragma unroll
    for (int T = 0; T < 4; ++T) acc[T] = (f32x4){bv_[T], bv_[T], bv_[T], bv_[T]};
#pragma unroll
    for (int c = 0; c < 8; ++c) {
      bf16x8 a_c = *(const bf16x8*)&abuf[pb][c][col][lgrp * 8];
      oacc = MFMA16(a_c, wout_[c], oacc);
#pragma unroll
      for (int T = 0; T < 4; ++T) acc[T] = MFMA16(a_c, wf_[T][c], acc[T]);
    }
    bf16x8 ax = (bf16x8){};
    if (j == 0) {
      if (lgrp == 0) {
        ax[0] = (__bf16)ix0; ax[1] = (__bf16)ix1; ax[2] = (__bf16)ix2;
        ax[3] = (__bf16)ix3; ax[4] = (__bf16)ix4;
      }
    } else {
      // out(j-1) = lrelu(W_out @ h_gen(j) + b_out); store + becomes x(j)
      if (col < 5) {
#pragma unroll
        for (int r = 0; r < 4; ++r) {
          float v = lrelu(oacc[r]);
          if (wv == 0) out[((size_t)(b0 + lgrp * 4 + r) * 128 + (j - 1)) * 5 + col] = v;
          xt[wv][lgrp * 4 + r][col] = (__bf16)v;  // wave-private transpose tile
        }
      }
      if (lgrp == 0) ax = *(const bf16x8*)&xt[wv][col][0];
    }
    if (j < 128) {
#pragma unroll
      for (int T = 0; T < 4; ++T) acc[T] = MFMA16(ax, wih_[T], acc[T]);
#pragma unroll
      for (int r = 0; r < 4; ++r) {
        float ig = fast_sigmoid(acc[0][r]);
        float fg = fast_sigmoid(acc[1][r]);
        float gg = fast_tanh(acc[2][r]);
        float og = fast_sigmoid(acc[3][r]);
        float cn = fg * c_reg[r] + ig * gg;
        c_reg[r] = cn;
        abuf[pb ^ 1][ci][lgrp * 4 + r][ko] = (__bf16)(og * fast_tanh(cn));
      }
    }
    __syncthreads();
  }
}

extern "C" void kernel_launch(void* const* d_in, const int* in_sizes, int n_in,
                              void* d_out, int out_size, void* d_ws, size_t ws_size,
                              hipStream_t stream) {
  const float* sk = (const float*)d_in[0];
  const float* initx = (const float*)d_in[1];
  const float* W_ih = (const float*)d_in[2];
  const float* W_hh = (const float*)d_in[3];
  const float* b_ih = (const float*)d_in[4];
  const float* b_hh = (const float*)d_in[5];
  const float* W_ih_f = (const float*)d_in[6];
  const float* W_hh_f = (const float*)d_in[7];
  const float* b_ih_f = (const float*)d_in[8];
  const float* b_hh_f = (const float*)d_in[9];
  const float* W_enc = (const float*)d_in[14];
  const float* b_enc = (const float*)d_in[15];
  const float* W_out = (const float*)d_in[16];
  const float* b_out = (const float*)d_in[17];

  char* ws = (char*)d_ws;
  __bf16* Wg = (__bf16*)(ws + 0);            // 524288
  __bf16* Wf = (__bf16*)(ws + 524288);       // 524288
  __bf16* IHg = (__bf16*)(ws + 1048576);     // 65536
  __bf16* IHf = (__bf16*)(ws + 1114112);     // 65536
  __bf16* Epk = (__bf16*)(ws + 1179648);     // 131072
  __bf16* Opk = (__bf16*)(ws + 1310720);     // 8192
  float* Bg = (float*)(ws + 1318912);        // 4096
  float* Bf = (float*)(ws + 1323008);        // 4096
  __bf16* hx = (__bf16*)(ws + 1327104);      // 4 MB
  unsigned int* flags = (unsigned int*)(ws + 5521408);  // 2048

  hipMemsetAsync(flags, 0, 2048, stream);
  pack_gates_k<<<592, 64, 0, stream>>>(W_hh, W_ih, b_ih, b_hh, Wg, IHg, Bg);
  pack_gates_k<<<592, 64, 0, stream>>>(W_hh_f, W_ih_f, b_ih_f, b_hh_f, Wf, IHf, Bf);
  pack_misc_k<<<136, 64, 0, stream>>>(W_enc, W_out, Epk, Opk);

  rnn_grp<<<512, 256, 0, stream>>>(
      sk, initx,
      (const bf16x8*)Wg, (const bf16x8*)IHg, Bg,
      (const bf16x8*)Wf, (const bf16x8*)IHf, Bf,
      (const bf16x8*)Epk, b_enc,
      (const bf16x8*)Opk, b_out,
      hx, flags, (float*)d_out);
}

// Round 4
// 1518.130 us; speedup vs baseline: 8.3377x; 8.3377x over previous
//
#include <hip/hip_runtime.h>

// B=2048, T=128, D=5, H=256. Two sequential LSTM scans.
// Round 4: fully-resident weights per CU. grid=128 WGs x 512 thr (8 waves),
// 1 WG/CU. Per phase: W_hh chunks 0..5 in REGISTERS (48 frags = 192 VGPR,
// asm-pinned), chunks 6,7 in LDS (128 KB, shared), W_ih dense 10 KB LDS,
// W_out frags 8 KB LDS, bias 4 KB LDS. h state in XOR-swizzled 8 KB LDS
// buffer; 2 barriers/step; zero cross-WG communication.

typedef __bf16 bf16x8 __attribute__((ext_vector_type(8)));
typedef __bf16 bf16x4 __attribute__((ext_vector_type(4)));
typedef float f32x4 __attribute__((ext_vector_type(4)));
typedef int i32x4 __attribute__((ext_vector_type(4)));

#define MFMA16(A, B, C) __builtin_amdgcn_mfma_f32_16x16x32_bf16((A), (B), (C), 0, 0, 0)

__device__ __forceinline__ float fast_sigmoid(float x) {
  float e = __builtin_amdgcn_exp2f(-1.4426950408889634f * x);
  return __builtin_amdgcn_rcpf(1.0f + e);
}
__device__ __forceinline__ float fast_tanh(float x) {
  float e = __builtin_amdgcn_exp2f(2.8853900817779268f * x);
  return 1.0f - 2.0f * __builtin_amdgcn_rcpf(e + 1.0f);
}
__device__ __forceinline__ float lrelu(float x) { return x >= 0.0f ? x : 0.01f * x; }

__device__ __forceinline__ bf16x8 asbf(i32x4 v) {
  union { i32x4 i; bf16x8 b; } u; u.i = v; return u.b;
}

// ---------------- prep: pack weights ----------------
// Whh frag (gt,c,lane): 8 bf16 = W[g=gt*16+(lane&15)][k=c*32+(lane>>4)*8+0..7]
__global__ void pack_gates_k(const float* __restrict__ Whh, const float* __restrict__ Wih,
                             const float* __restrict__ bih, const float* __restrict__ bhh,
                             __bf16* __restrict__ wpack, __bf16* __restrict__ wih4,
                             __bf16* __restrict__ wihd4, float* __restrict__ bias) {
  int lane = threadIdx.x, blk = blockIdx.x;
  if (blk < 512) {
    int gt = blk >> 3, c = blk & 7;
    int g = gt * 16 + (lane & 15);
    int k0 = c * 32 + (lane >> 4) * 8;
    bf16x8 v;
#pragma unroll
    for (int j = 0; j < 8; ++j) v[j] = (__bf16)Whh[g * 256 + k0 + j];
    *(bf16x8*)(wpack + ((size_t)(gt * 8 + c) * 64 + lane) * 8) = v;
  } else if (blk < 528) {
    int g = (blk - 512) * 64 + lane;
    bf16x4 v;
#pragma unroll
    for (int j = 0; j < 4; ++j) v[j] = (__bf16)Wih[g * 5 + j];
    *(bf16x4*)(wih4 + (size_t)g * 4) = v;
    wihd4[g] = (__bf16)Wih[g * 5 + 4];
  } else {
    int g = (blk - 528) * 64 + lane;
    bias[g] = bih[g] + bhh[g];
  }
}

__global__ void pack_misc_k(const float* __restrict__ Wenc, const float* __restrict__ Wout,
                            __bf16* __restrict__ encpack, __bf16* __restrict__ outpack) {
  int lane = threadIdx.x, blk = blockIdx.x;
  if (blk < 128) {  // W_enc[:, :256]: 16 row-tiles x 8 chunks
    int T2 = blk >> 3, c = blk & 7;
    int row = T2 * 16 + (lane & 15);
    int k0 = c * 32 + (lane >> 4) * 8;
    bf16x8 v;
#pragma unroll
    for (int j = 0; j < 8; ++j) v[j] = (__bf16)Wenc[row * 512 + k0 + j];
    *(bf16x8*)(encpack + ((size_t)(T2 * 8 + c) * 64 + lane) * 8) = v;
  } else {  // W_out (5x256) zero-padded to 16 rows
    int c = blk - 128;
    int d = lane & 15, k0 = c * 32 + (lane >> 4) * 8;
    bf16x8 v;
#pragma unroll
    for (int j = 0; j < 8; ++j)
      v[j] = (d < 5) ? (__bf16)Wout[d * 256 + k0 + j] : (__bf16)0.0f;
    *(bf16x8*)(outpack + ((size_t)c * 64 + lane) * 8) = v;
  }
}

// ---------------- main kernel ----------------
__global__ __launch_bounds__(512, 2) void rnn_res(
    const float* __restrict__ sk, const float* __restrict__ initx,
    const i32x4* __restrict__ Wg, const __bf16* __restrict__ Wih4g, const __bf16* __restrict__ Wihd4g,
    const float* __restrict__ Bg,
    const i32x4* __restrict__ Wf, const __bf16* __restrict__ Wih4f, const __bf16* __restrict__ Wihd4f,
    const float* __restrict__ Bf,
    const bf16x8* __restrict__ Epk, const float* __restrict__ benc,
    const i32x4* __restrict__ Opk, const float* __restrict__ bout,
    float* __restrict__ out) {
  __shared__ __attribute__((aligned(16))) __bf16 wlds[2][64][64][8];  // 131072 B: Whh chunks 6,7
  __shared__ __attribute__((aligned(16))) __bf16 wih4s[1024][4];      // 8192 B
  __shared__ __attribute__((aligned(16))) __bf16 wouts[8][64][8];     // 8192 B
  __shared__ __attribute__((aligned(16))) __bf16 hb[4096];            // 8192 B: h [16 rows][256 u], XOR-swizzled
  __shared__ __attribute__((aligned(16))) float biass[1024];          // 4096 B
  __shared__ __attribute__((aligned(16))) __bf16 wihd4s[1024];        // 2048 B
  __shared__ __attribute__((aligned(8)))  __bf16 xts[8][16][4];       // 1024 B
  __shared__ __attribute__((aligned(8)))  __bf16 xd4s[8][16];         // 256 B

  const int tid = threadIdx.x, lane = tid & 63, wv = tid >> 6;
  const int col = lane & 15, lgrp = lane >> 4;
  const int b0 = blockIdx.x * 16;
  const int xsw = (col & 7) << 4;  // read-side swizzle for this lane
  char* hbb = (char*)hb;

  // ---------- staging helpers ----------
  auto stage_wlds = [&](const i32x4* Wpk) {
    for (int i = tid; i < 8192; i += 512) {
      int c2 = i >> 12, gt = (i >> 6) & 63, ln = i & 63;
      i32x4 v = Wpk[(gt * 8 + 6 + c2) * 64 + ln];
      *(i32x4*)&wlds[c2][gt][ln][0] = v;
    }
  };
  auto stage_small = [&](const __bf16* w4, const __bf16* wd4, const float* Bp) {
    for (int i = tid; i < 1024; i += 512) {
      *(bf16x4*)&wih4s[i][0] = *(const bf16x4*)(w4 + (size_t)i * 4);
      biass[i] = Bp[i];
    }
    for (int i = tid; i < 512; i += 512)
      ((uint*)wihd4s)[i] = ((const uint*)wd4)[i];  // 1024 bf16 as 512 uints
    if (tid < 512) ((uint*)wihd4s)[tid] = ((const uint*)wd4)[tid];
  };

  // ---------- encoder prologue ----------
  stage_wlds(Wf);
  stage_small(Wih4f, Wihd4f, Bf);
  for (int i = tid; i < 4096; i += 512) hb[i] = (__bf16)0.0f;

  // register-resident Whh chunks 0..5 (48 frags = 192 VGPR), pinned
  i32x4 wr[48];
#pragma unroll
  for (int q = 0; q < 4; ++q)
#pragma unroll
    for (int p = 0; p < 2; ++p) {
      const int gt = q * 16 + wv * 2 + p;
#pragma unroll
      for (int c = 0; c < 6; ++c) wr[(q * 2 + p) * 6 + c] = Wf[(gt * 8 + c) * 64 + lane];
    }
#pragma unroll
  for (int i = 0; i < 48; ++i) asm volatile("" : "+v"(wr[i]));

  float c_reg[2][4] = {{0.f, 0.f, 0.f, 0.f}, {0.f, 0.f, 0.f, 0.f}};
  float xc0 = 0.f, xc1 = 0.f, xc2 = 0.f, xc3 = 0.f, xc4 = 0.f;
  if (lgrp == 0) {
    const float* xp = sk + (size_t)(b0 + col) * 128 * 5;
    xc0 = xp[0]; xc1 = xp[1]; xc2 = xp[2]; xc3 = xp[3]; xc4 = xp[4];
  }
  __syncthreads();

  // one gate pass: reads h from hb, accumulates gates for (q=0..3, given p),
  // using reg chunks 0..5, LDS chunks 6..7, and the x chunk.
#define GATEPASS(P, AX, HV)                                                          \
  {                                                                                  \
    const int gt0 = 0 * 16 + wv * 2 + (P), gt1 = 1 * 16 + wv * 2 + (P);              \
    const int gt2 = 2 * 16 + wv * 2 + (P), gt3 = 3 * 16 + wv * 2 + (P);              \
    float bv0 = biass[gt0 * 16 + col], bv1 = biass[gt1 * 16 + col];                  \
    float bv2 = biass[gt2 * 16 + col], bv3 = biass[gt3 * 16 + col];                  \
    f32x4 a0 = {bv0, bv0, bv0, bv0}, a1 = {bv1, bv1, bv1, bv1};                      \
    f32x4 a2 = {bv2, bv2, bv2, bv2}, a3 = {bv3, bv3, bv3, bv3};                      \
    _Pragma("unroll") for (int c = 0; c < 6; ++c) {                                  \
      bf16x8 ac = *(const bf16x8*)(hbb + ((col * 512 + c * 64 + lgrp * 16) ^ xsw));  \
      a0 = MFMA16(ac, asbf(wr[(0 * 2 + (P)) * 6 + c]), a0);                          \
      a1 = MFMA16(ac, asbf(wr[(1 * 2 + (P)) * 6 + c]), a1);                          \
      a2 = MFMA16(ac, asbf(wr[(2 * 2 + (P)) * 6 + c]), a2);                          \
      a3 = MFMA16(ac, asbf(wr[(3 * 2 + (P)) * 6 + c]), a3);                          \
    }                                                                                \
    _Pragma("unroll") for (int c = 6; c < 8; ++c) {                                  \
      bf16x8 ac = *(const bf16x8*)(hbb + ((col * 512 + c * 64 + lgrp * 16) ^ xsw));  \
      a0 = MFMA16(ac, *(const bf16x8*)&wlds[c - 6][gt0][lane][0], a0);               \
      a1 = MFMA16(ac, *(const bf16x8*)&wlds[c - 6][gt1][lane][0], a1);               \
      a2 = MFMA16(ac, *(const bf16x8*)&wlds[c - 6][gt2][lane][0], a2);               \
      a3 = MFMA16(ac, *(const bf16x8*)&wlds[c - 6][gt3][lane][0], a3);               \
    }                                                                                \
    { /* x chunk: B-frag nonzero only for lgrp==0 (k<8) */                           \
      bf16x8 b0f = {}, b1f = {}, b2f = {}, b3f = {};                                 \
      if (lgrp == 0) {                                                               \
        bf16x4 w40 = *(const bf16x4*)&wih4s[gt0 * 16 + col][0];                      \
        bf16x4 w41 = *(const bf16x4*)&wih4s[gt1 * 16 + col][0];                      \
        bf16x4 w42 = *(const bf16x4*)&wih4s[gt2 * 16 + col][0];                      \
        bf16x4 w43 = *(const bf16x4*)&wih4s[gt3 * 16 + col][0];                      \
        b0f[0]=w40[0]; b0f[1]=w40[1]; b0f[2]=w40[2]; b0f[3]=w40[3];                  \
        b1f[0]=w41[0]; b1f[1]=w41[1]; b1f[2]=w41[2]; b1f[3]=w41[3];                  \
        b2f[0]=w42[0]; b2f[1]=w42[1]; b2f[2]=w42[2]; b2f[3]=w42[3];                  \
        b3f[0]=w43[0]; b3f[1]=w43[1]; b3f[2]=w43[2]; b3f[3]=w43[3];                  \
        b0f[4]=wihd4s[gt0 * 16 + col]; b1f[4]=wihd4s[gt1 * 16 + col];                \
        b2f[4]=wihd4s[gt2 * 16 + col]; b3f[4]=wihd4s[gt3 * 16 + col];                \
      }                                                                              \
      a0 = MFMA16(AX, b0f, a0); a1 = MFMA16(AX, b1f, a1);                            \
      a2 = MFMA16(AX, b2f, a2); a3 = MFMA16(AX, b3f, a3);                            \
    }                                                                                \
    _Pragma("unroll") for (int r = 0; r < 4; ++r) {                                  \
      float ig = fast_sigmoid(a0[r]);                                                \
      float fg = fast_sigmoid(a1[r]);                                                \
      float gg = fast_tanh(a2[r]);                                                   \
      float og = fast_sigmoid(a3[r]);                                                \
      float cn = fg * c_reg[P][r] + ig * gg;                                         \
      c_reg[P][r] = cn;                                                              \
      HV[r] = og * fast_tanh(cn);                                                    \
    }                                                                                \
  }

#define HWRITE(P, HV)                                                                \
  _Pragma("unroll") for (int r = 0; r < 4; ++r) {                                    \
    const int row = lgrp * 4 + r;                                                    \
    const int u = 32 * wv + 16 * (P) + col;                                          \
    *(__bf16*)(hbb + ((row * 512 + u * 2) ^ ((row & 7) << 4))) = (__bf16)HV[r];      \
  }

  // -------- encoder: 128 steps, 2 barriers/step --------
  for (int t = 0; t < 128; ++t) {
    bf16x8 ax = {};
    if (lgrp == 0) {
      ax[0] = (__bf16)xc0; ax[1] = (__bf16)xc1; ax[2] = (__bf16)xc2;
      ax[3] = (__bf16)xc3; ax[4] = (__bf16)xc4;
    }
    if (t < 127 && lgrp == 0) {  // prefetch x(t+1), overlaps MFMA below
      const float* xp = sk + ((size_t)(b0 + col) * 128 + t + 1) * 5;
      xc0 = xp[0]; xc1 = xp[1]; xc2 = xp[2]; xc3 = xp[3]; xc4 = xp[4];
    }
    float hv0[4], hv1[4];
    GATEPASS(0, ax, hv0);
    GATEPASS(1, ax, hv1);
    __syncthreads();  // all reads of h(t) done
    HWRITE(0, hv0);
    HWRITE(1, hv1);
    __syncthreads();  // h(t+1) visible
  }

  // -------- transition --------
  bf16x8 ah[8];
#pragma unroll
  for (int c = 0; c < 8; ++c)
    ah[c] = *(const bf16x8*)(hbb + ((col * 512 + c * 64 + lgrp * 16) ^ xsw));
  __syncthreads();
#pragma unroll
  for (int p = 0; p < 2; ++p)
#pragma unroll
    for (int r = 0; r < 4; ++r) {
      const int row = lgrp * 4 + r, u = 32 * wv + 16 * p + col;
      *(__bf16*)(hbb + ((row * 512 + u * 2) ^ ((row & 7) << 4))) = (__bf16)c_reg[p][r];
    }
  __syncthreads();
  bf16x8 acf[8];
#pragma unroll
  for (int c = 0; c < 8; ++c)
    acf[c] = *(const bf16x8*)(hbb + ((col * 512 + c * 64 + lgrp * 16) ^ xsw));
  __syncthreads();  // hb free for hidden

  float hvv[2][4];
#pragma unroll
  for (int p = 0; p < 2; ++p) {
    const int T2 = wv * 2 + p;
    const float bvh = benc[T2 * 16 + col];
    f32x4 hacc = {bvh, bvh, bvh, bvh};
    f32x4 cacc = {bvh, bvh, bvh, bvh};
#pragma unroll
    for (int c = 0; c < 8; ++c) {
      bf16x8 eb = Epk[(T2 * 8 + c) * 64 + lane];
      hacc = MFMA16(ah[c], eb, hacc);
      cacc = MFMA16(acf[c], eb, cacc);
    }
#pragma unroll
    for (int r = 0; r < 4; ++r) {
      hvv[p][r] = lrelu(hacc[r]);
      c_reg[p][r] = lrelu(cacc[r]);  // gen c(0): same wave owns these units
    }
  }
#pragma unroll
  for (int p = 0; p < 2; ++p) HWRITE(p, hvv[p]);  // gen h(0)

  // restage LDS + registers for generator
  stage_wlds(Wg);
  stage_small(Wih4g, Wihd4g, Bg);
  for (int i = tid; i < 512; i += 512) *(i32x4*)&wouts[0][0][i * 8] = Opk[i];
  if (tid < 512) *(i32x4*)(((i32x4*)&wouts[0][0][0]) + tid) = Opk[tid];
#pragma unroll
  for (int q = 0; q < 4; ++q)
#pragma unroll
    for (int p = 0; p < 2; ++p) {
      const int gt = q * 16 + wv * 2 + p;
#pragma unroll
      for (int c = 0; c < 6; ++c) wr[(q * 2 + p) * 6 + c] = Wg[(gt * 8 + c) * 64 + lane];
    }
#pragma unroll
  for (int i = 0; i < 48; ++i) asm volatile("" : "+v"(wr[i]));

  const float bo = (col < 5) ? bout[col] : 0.0f;
  bf16x8 ax = {};
  if (lgrp == 0) {
    const float* xp = initx + (size_t)(b0 + col) * 5;
    ax[0] = (__bf16)xp[0]; ax[1] = (__bf16)xp[1]; ax[2] = (__bf16)xp[2];
    ax[3] = (__bf16)xp[3]; ax[4] = (__bf16)xp[4];
  }
  __syncthreads();  // hidden + stages visible

  // -------- generator: 128 steps --------
  for (int j = 0; j < 128; ++j) {
    float hv0[4], hv1[4];
    GATEPASS(0, ax, hv0);
    GATEPASS(1, ax, hv1);
    __syncthreads();  // reads of h(j) done
    HWRITE(0, hv0);
    HWRITE(1, hv1);
    __syncthreads();  // h(j+1) visible
    // out(j) = lrelu(W_out @ h(j+1) + b_out), redundant on all waves
    f32x4 oacc = {bo, bo, bo, bo};
#pragma unroll
    for (int c = 0; c < 8; ++c) {
      bf16x8 ac = *(const bf16x8*)(hbb + ((col * 512 + c * 64 + lgrp * 16) ^ xsw));
      oacc = MFMA16(ac, *(const bf16x8*)&wouts[c][lane][0], oacc);
    }
    if (col < 5) {
#pragma unroll
      for (int r = 0; r < 4; ++r) {
        float v = lrelu(oacc[r]);
        if (wv == 0) out[((size_t)(b0 + lgrp * 4 + r) * 128 + j) * 5 + col] = v;
        __bf16 vb = (__bf16)v;
        if (col < 4) xts[wv][lgrp * 4 + r][col] = vb;
        else         xd4s[wv][lgrp * 4 + r] = vb;
      }
    }
    // x(j+1) frag from wave-private transpose tile (same-wave ds ordering)
    ax = (bf16x8){};
    if (lgrp == 0) {
      bf16x4 lo = *(const bf16x4*)&xts[wv][col][0];
      ax[0] = lo[0]; ax[1] = lo[1]; ax[2] = lo[2]; ax[3] = lo[3];
      ax[4] = xd4s[wv][col];
    }
  }
}

extern "C" void kernel_launch(void* const* d_in, const int* in_sizes, int n_in,
                              void* d_out, int out_size, void* d_ws, size_t ws_size,
                              hipStream_t stream) {
  const float* sk = (const float*)d_in[0];
  const float* initx = (const float*)d_in[1];
  const float* W_ih = (const float*)d_in[2];
  const float* W_hh = (const float*)d_in[3];
  const float* b_ih = (const float*)d_in[4];
  const float* b_hh = (const float*)d_in[5];
  const float* W_ih_f = (const float*)d_in[6];
  const float* W_hh_f = (const float*)d_in[7];
  const float* b_ih_f = (const float*)d_in[8];
  const float* b_hh_f = (const float*)d_in[9];
  const float* W_enc = (const float*)d_in[14];
  const float* b_enc = (const float*)d_in[15];
  const float* W_out = (const float*)d_in[16];
  const float* b_out = (const float*)d_in[17];

  char* ws = (char*)d_ws;
  __bf16* Wg = (__bf16*)(ws + 0);            // 524288
  __bf16* Wf = (__bf16*)(ws + 524288);       // 524288
  __bf16* Wih4g = (__bf16*)(ws + 1048576);   // 8192
  __bf16* Wihd4g = (__bf16*)(ws + 1056768);  // 2048
  __bf16* Wih4f = (__bf16*)(ws + 1058816);   // 8192
  __bf16* Wihd4f = (__bf16*)(ws + 1067008);  // 2048
  float* Bg = (float*)(ws + 1069056);        // 4096
  float* Bf = (float*)(ws + 1073152);        // 4096
  __bf16* Epk = (__bf16*)(ws + 1077248);     // 131072
  __bf16* Opk = (__bf16*)(ws + 1208320);     // 8192

  pack_gates_k<<<544, 64, 0, stream>>>(W_hh, W_ih, b_ih, b_hh, Wg, Wih4g, Wihd4g, Bg);
  pack_gates_k<<<544, 64, 0, stream>>>(W_hh_f, W_ih_f, b_ih_f, b_hh_f, Wf, Wih4f, Wihd4f, Bf);
  pack_misc_k<<<136, 64, 0, stream>>>(W_enc, W_out, Epk, Opk);

  rnn_res<<<128, 512, 0, stream>>>(
      sk, initx,
      (const i32x4*)Wg, Wih4g, Wihd4g, Bg,
      (const i32x4*)Wf, Wih4f, Wihd4f, Bf,
      (const bf16x8*)Epk, b_enc,
      (const i32x4*)Opk, b_out,
      (float*)d_out);
}